// Round 7
// baseline (1501.439 us; speedup 1.0000x reference)
//
#include <hip/hip_runtime.h>

#define TSTEPS 336
#define NI 24
#define NH 128
#define RW 8           // batch rows per workgroup (M=16 MFMA half-used; 2 WG/CU)
#define NTHREADS 512
#define NWG 512        // 4096 / RW

typedef __attribute__((ext_vector_type(8))) short bf16x8;
typedef __attribute__((ext_vector_type(4))) float f32x4;
typedef unsigned short u16;
typedef unsigned int u32;

struct __align__(16) Smem {
    u16 hhi[2][4][72][8];               // 9216  h frags (hi only), dbuf, phi-swizzled slots
    u16 chi[64][8], clo[64][8];         // 2048  c hi/lo A-frags (K-pad lanes stay zero)
    u16 x1hi[2][64][8], x2hi[2][64][8]; // 4096  x A-frags (hi only), dbuf
    float xt[2][8][52];                 // 3328  x staging, padded rows
    float exw1h[16][26], exs1[16][26], exs2[16][26]; // 4992 (rows 8-15 = dead-lane spill)
};                                      // 23680 B -> 2 WG/CU
static_assert(sizeof(Smem) <= 65536, "LDS overflow");

__device__ __forceinline__ u16 f2bf(float f) {
    u32 u = __float_as_uint(f);
    return (u16)((u + 0x7FFFu + ((u >> 16) & 1u)) >> 16);
}
__device__ __forceinline__ float bf2f(u16 h) { return __uint_as_float(((u32)h) << 16); }
__device__ __forceinline__ float frcp(float x) { return __builtin_amdgcn_rcpf(x); }
__device__ __forceinline__ float fex2(float x) { return __builtin_amdgcn_exp2f(x); }
__device__ __forceinline__ float sigm(float x) { return frcp(1.0f + fex2(-1.4426950408889634f * x)); }
__device__ __forceinline__ float tanhf_(float x) { return 1.0f - 2.0f * frcp(1.0f + fex2(2.8853900817779268f * x)); }
__device__ __forceinline__ float fexp(float x) { return fex2(1.4426950408889634f * x); }

// pack 8 consecutive f32 -> bf16x8 (RNE, same rounding as LDS path)
__device__ __forceinline__ bf16x8 ldfrag(const float* __restrict__ p) {
    float4 a = *(const float4*)p;
    float4 b = *(const float4*)(p + 4);
    union { u32 u[4]; bf16x8 v; } r;
    r.u[0] = (u32)f2bf(a.x) | ((u32)f2bf(a.y) << 16);
    r.u[1] = (u32)f2bf(a.z) | ((u32)f2bf(a.w) << 16);
    r.u[2] = (u32)f2bf(b.x) | ((u32)f2bf(b.y) << 16);
    r.u[3] = (u32)f2bf(b.z) | ((u32)f2bf(b.w) << 16);
    return r.v;
}

// LDS-only barrier: global prefetch stays in flight
__device__ __forceinline__ void bar() {
    asm volatile("s_waitcnt lgkmcnt(0)" ::: "memory");
    __builtin_amdgcn_s_barrier();
    asm volatile("" ::: "memory");
}

#define MFMA(A, B, C) __builtin_amdgcn_mfma_f32_16x16x32_bf16((A), (B), (C), 0, 0, 0)

__global__ __launch_bounds__(NTHREADS, 4) void gru_persist(
    const float* __restrict__ x, const float* __restrict__ wih, const float* __restrict__ whh,
    const float* __restrict__ bih, const float* __restrict__ bhh,
    const float* __restrict__ h2ow, const float* __restrict__ h2ob_p,
    const float* __restrict__ w1w, const float* __restrict__ w1b_p,
    const float* __restrict__ w2w, const float* __restrict__ w2b_p,
    float* __restrict__ out)
{
    __shared__ Smem S;
    const int tid = threadIdx.x;
    const int l = tid & 63;
    const int w = tid >> 6;
    const int g = l >> 4;
    const int cl = l & 15;
    const int b0 = blockIdx.x * RW;

    // ---- zero LDS (K-pad lanes of frags must be 0; rest hygiene) ----
    for (int i = tid; i < (int)(sizeof(Smem) / 4); i += NTHREADS) ((u32*)&S)[i] = 0u;

    // ---- weights: global -> persistent registers (no LDS staging) ----
    const bf16x8 zf = {0, 0, 0, 0, 0, 0, 0, 0};
    bf16x8 wihR[3], whhR[3][4], headR[4];
#pragma unroll
    for (int s = 0; s < 3; ++s) {
        const int tw = w + 8 * s;                    // gate col-tile (r: 0-7, z: 8-15, n: 16-23)
        wihR[s] = (l < 48) ? ldfrag(wih + (16 * tw + cl) * NI + 8 * g) : zf;
#pragma unroll
        for (int kt = 0; kt < 4; ++kt)
            whhR[s][kt] = ldfrag(whh + (16 * tw + cl) * NH + 32 * kt + 8 * g);
    }
    if (w < 2) {                                     // W1 tile w (cols 16-23 only on w1/cl<8)
#pragma unroll
        for (int kt = 0; kt < 4; ++kt)
            headR[kt] = (w == 0 || cl < 8) ? ldfrag(w1w + (16 * w + cl) * NH + 32 * kt + 8 * g) : zf;
    } else if (w == 2) {                             // h2o as B-frag col 0
#pragma unroll
        for (int kt = 0; kt < 4; ++kt)
            headR[kt] = (cl == 0) ? ldfrag(h2ow + 32 * kt + 8 * g) : zf;
    } else {                                         // W2 tiles 0,1 (K=24)
        headR[0] = (g < 3) ? ldfrag(w2w + cl * NI + 8 * g) : zf;
        headR[1] = (g < 3 && cl < 8) ? ldfrag(w2w + (16 + cl) * NI + 8 * g) : zf;
        headR[2] = zf;
        headR[3] = zf;
    }

    // per-lane constants
    const float bR  = bih[w * 16 + cl] + bhh[w * 16 + cl];
    const float bZ  = bih[128 + w * 16 + cl] + bhh[128 + w * 16 + cl];
    const float bxN = bih[256 + w * 16 + cl];
    const float bhN = bhh[256 + w * 16 + cl];
    const float w1bias = (w == 0) ? w1b_p[cl] : ((w == 1 && cl < 8) ? w1b_p[16 + cl] : 0.0f);
    const float w2b0 = w2b_p[cl];
    const float w2b1 = (cl < 8) ? w2b_p[16 + cl] : 0.0f;
    const float h2ob = h2ob_p[0];

    // h ownership + phi-swizzle (phi(p) = p + ((p>>3)&1) + 2*(p>>4))
    const int ktH = w >> 1;
    const int cc = (2 * w + (cl >> 3)) & 3;
    const int hsB0 = 4 * g + 16 * cc + (g >> 1) + 2 * cc;
    const int eH = cl & 7;
    const int hsl = l + ((l >> 3) & 1) + 2 * (l >> 4);
    float h_reg[4] = {0.f, 0.f, 0.f, 0.f};

    bar();   // LDS zeroed

    // x(t=0) staging (8 rows x 48 cols)
    if (tid < 96) {
        const float* src = x + ((size_t)(b0 + tid / 12) * TSTEPS) * 48 + (tid % 12) * 4;
        *(float4*)&S.xt[0][tid / 12][(tid % 12) * 4] = *(const float4*)src;
    }
    bar();

    // build c(0)=h1(0) and x(0) fragments (rows 0-7)
    if (tid < 192) {
        int rr = tid & 7, j = tid >> 3;
        float h1 = S.xt[0][rr][j];
        float h2 = S.xt[0][rr][24 + j];
        int lane = rr + (j >> 3) * 16, el = j & 7;
        u16 hi = f2bf(h1);
        S.chi[lane][el] = hi;  S.clo[lane][el] = f2bf(h1 - bf2f(hi));
        S.x1hi[0][lane][el] = hi;
        S.x2hi[0][lane][el] = f2bf(h2);
    }
    float4 xfA, xfB;
    if (tid < 96) {
        const float* src = x + ((size_t)(b0 + tid / 12) * TSTEPS + 1) * 48 + (tid % 12) * 4;
        xfA = *(const float4*)src;
    }
    // gh(0) carry: h(-1)=0 -> biases only
    f32x4 gR = {bR, bR, bR, bR};
    f32x4 gZ = {bZ, bZ, bZ, bZ};
    f32x4 gN = {bhN, bhN, bhN, bhN};
    __syncthreads();

    for (int t = 0; t < TSTEPS; ++t) {
        const int cb = t & 1;
        const int nxt = (t + 1) & 1;
        const bool ld2 = (tid < 96) && (t + 2 < TSTEPS);
        const bool st1 = (tid < 96) && (t + 1 < TSTEPS);
        if (ld2) {
            const float* src = x + ((size_t)(b0 + tid / 12) * TSTEPS + (t + 2)) * 48 + (tid % 12) * 4;
            xfB = *(const float4*)src;
        }
        // ---- P1: finish gates with c(t); gR/gZ/gN carry h-part from prev tail ----
        f32x4 aN = {bxN, bxN, bxN, bxN};
        {
            bf16x8 cH = *(const bf16x8*)&S.chi[l][0];
            bf16x8 cL = *(const bf16x8*)&S.clo[l][0];
            gR = MFMA(cH, wihR[0], gR);  gR = MFMA(cL, wihR[0], gR);
            gZ = MFMA(cH, wihR[1], gZ);  gZ = MFMA(cL, wihR[1], gZ);
            aN = MFMA(cH, wihR[2], aN);  aN = MFMA(cL, wihR[2], aN);
        }
        if (w == 4 || w == 5) {     // s1/s2 x-parts from x(t) frags (buffer cb)
            bf16x8 aH = (w == 4) ? *(const bf16x8*)&S.x1hi[cb][l][0]
                                 : *(const bf16x8*)&S.x2hi[cb][l][0];
            f32x4 a0 = {w2b0, w2b0, w2b0, w2b0};
            f32x4 a1v = {w2b1, w2b1, w2b1, w2b1};
            a0 = MFMA(aH, headR[0], a0);
            a1v = MFMA(aH, headR[1], a1v);
            float(*ex)[26] = (w == 4) ? S.exs1 : S.exs2;
#pragma unroll
            for (int i = 0; i < 4; ++i) ex[4 * g + i][cl] = a0[i];
            if (cl < 8) {
#pragma unroll
                for (int i = 0; i < 4; ++i) ex[4 * g + i][16 + cl] = a1v[i];
            }
        }
        // gates; h_old in registers; store h(t) (hi only) to buffer cb
#pragma unroll
        for (int i = 0; i < 4; ++i) {
            float r = sigm(gR[i]);
            float z = sigm(gZ[i]);
            float n = tanhf_(aN[i] + r * gN[i]);
            float hv = (1.0f - z) * n + z * h_reg[i];
            h_reg[i] = hv;
            S.hhi[cb][ktH][hsB0 + i][eH] = f2bf(hv);
        }
        // x(t+1): stage to xt + build x-frags (buffer nxt) from registers
        if (st1) {
            *(float4*)&S.xt[nxt][tid / 12][(tid % 12) * 4] = xfA;
            int row = tid / 12, col0 = (tid % 12) * 4;
            int jj0 = (col0 < 24) ? col0 : col0 - 24;
            int lane = row + (jj0 >> 3) * 16, el0 = jj0 & 7;   // el0 in {0,4}
            u16* dst = (col0 < 24) ? &S.x1hi[nxt][lane][el0] : &S.x2hi[nxt][lane][el0];
            u32 lo = (u32)f2bf(xfA.x) | ((u32)f2bf(xfA.y) << 16);
            u32 hi = (u32)f2bf(xfA.z) | ((u32)f2bf(xfA.w) << 16);
            *(u32*)dst = lo;
            *(u32*)(dst + 2) = hi;
        }
        xfA = xfB;
        bar(); // B3: h(t), x(t+1) frags, exs visible
        // ---- tail: gh(t+1) on all waves (hi only); heads ride the same registers ----
        gR = (f32x4){bR, bR, bR, bR};
        gZ = (f32x4){bZ, bZ, bZ, bZ};
        gN = (f32x4){bhN, bhN, bhN, bhN};
        f32x4 hacc = (w < 2) ? (f32x4){w1bias, w1bias, w1bias, w1bias}
                             : (f32x4){0.f, 0.f, 0.f, 0.f};
#pragma unroll
        for (int kt = 0; kt < 4; ++kt) {
            bf16x8 hH = *(const bf16x8*)&S.hhi[cb][kt][hsl][0];
            gR = MFMA(hH, whhR[0][kt], gR);
            gZ = MFMA(hH, whhR[1][kt], gZ);
            gN = MFMA(hH, whhR[2][kt], gN);
            if (w < 3) hacc = MFMA(hH, headR[kt], hacc);
        }
        if (w < 2) {
            int col = w * 16 + cl;
            if (col < 24) {
#pragma unroll
                for (int i = 0; i < 4; ++i) S.exw1h[4 * g + i][col] = hacc[i];
            }
        } else if (w == 2) {
            if (cl == 0 && g < 2) {      // rows 0-7 only (rows 8-15 are dead lanes)
#pragma unroll
                for (int i = 0; i < 4; ++i)
                    out[(size_t)(b0 + 4 * g + i) * TSTEPS + t] = tanhf_(hacc[i] + h2ob);
            }
        }
        bar(); // B4: exw1h visible
        // ---- phase 3 (192 thr, rows 0-7): a(t+1) -> c(t+1) frags ----
        if (tid < 192) {
            int rr = tid & 7, j = tid >> 3;
            float v = S.exw1h[rr][j];
            float e1 = fexp(tanhf_(v + S.exs1[rr][j]));
            float e2 = fexp(tanhf_(v + S.exs2[rr][j]));
            float inv = frcp(e1 + e2);
            float h1 = S.xt[nxt][rr][j];
            float h2 = S.xt[nxt][rr][24 + j];
            float cv = (e1 * inv) * h1 + (e2 * inv) * h2;
            int lane = rr + (j >> 3) * 16, el = j & 7;
            u16 hi = f2bf(cv);
            S.chi[lane][el] = hi;
            S.clo[lane][el] = f2bf(cv - bf2f(hi));
        }
        bar(); // B5: c frags ready for next P1
    }
}

extern "C" void kernel_launch(void* const* d_in, const int* in_sizes, int n_in,
                              void* d_out, int out_size, void* d_ws, size_t ws_size,
                              hipStream_t stream) {
    const float* x    = (const float*)d_in[0];
    const float* wih  = (const float*)d_in[1];
    const float* whh  = (const float*)d_in[2];
    const float* bih  = (const float*)d_in[3];
    const float* bhh  = (const float*)d_in[4];
    const float* h2ow = (const float*)d_in[5];
    const float* h2ob = (const float*)d_in[6];
    const float* w1w  = (const float*)d_in[7];
    const float* w1b  = (const float*)d_in[8];
    const float* w2w  = (const float*)d_in[9];
    const float* w2b  = (const float*)d_in[10];
    float* out = (float*)d_out;

    gru_persist<<<NWG, NTHREADS, 0, stream>>>(x, wih, whh, bih, bhh,
                                              h2ow, h2ob, w1w, w1b, w2w, w2b, out);
}

// Round 9
// 817.983 us; speedup vs baseline: 1.8355x; 1.8355x over previous
//
#include <hip/hip_runtime.h>

#define TSTEPS 336
#define NI 24
#define NH 128
#define RW 8           // batch rows per workgroup (M=16 MFMA half-used; 2 WG/CU)
#define NTHREADS 512
#define NWG 512        // 4096 / RW

typedef __attribute__((ext_vector_type(8))) short bf16x8;
typedef __attribute__((ext_vector_type(4))) float f32x4;
typedef unsigned short u16;
typedef unsigned int u32;

struct __align__(16) Smem {
    u16 hhi[2][4][72][8];               // 9216  h frags (hi only), dbuf, phi-swizzled slots
    u16 chi[64][8], clo[64][8];         // 2048  c hi/lo A-frags (K-pad lanes stay zero)
    u16 x1hi[2][64][8], x2hi[2][64][8]; // 4096  x A-frags (hi only), dbuf
    float xt[2][8][52];                 // 3328  x staging, padded rows
    float exw1h[16][26], exs1[16][26], exs2[16][26]; // 4992 (rows 8-15 = dead-lane spill)
};                                      // 23680 B -> 2 WG/CU (LDS-wise)
static_assert(sizeof(Smem) <= 65536, "LDS overflow");

__device__ __forceinline__ u16 f2bf(float f) {
    u32 u = __float_as_uint(f);
    return (u16)((u + 0x7FFFu + ((u >> 16) & 1u)) >> 16);
}
__device__ __forceinline__ float bf2f(u16 h) { return __uint_as_float(((u32)h) << 16); }
__device__ __forceinline__ float frcp(float x) { return __builtin_amdgcn_rcpf(x); }
__device__ __forceinline__ float fex2(float x) { return __builtin_amdgcn_exp2f(x); }
__device__ __forceinline__ float sigm(float x) { return frcp(1.0f + fex2(-1.4426950408889634f * x)); }
__device__ __forceinline__ float tanhf_(float x) { return 1.0f - 2.0f * frcp(1.0f + fex2(2.8853900817779268f * x)); }
__device__ __forceinline__ float fexp(float x) { return fex2(1.4426950408889634f * x); }

// pack 8 consecutive f32 -> bf16x8 (RNE, same rounding as LDS path)
__device__ __forceinline__ bf16x8 ldfrag(const float* __restrict__ p) {
    float4 a = *(const float4*)p;
    float4 b = *(const float4*)(p + 4);
    union { u32 u[4]; bf16x8 v; } r;
    r.u[0] = (u32)f2bf(a.x) | ((u32)f2bf(a.y) << 16);
    r.u[1] = (u32)f2bf(a.z) | ((u32)f2bf(a.w) << 16);
    r.u[2] = (u32)f2bf(b.x) | ((u32)f2bf(b.y) << 16);
    r.u[3] = (u32)f2bf(b.z) | ((u32)f2bf(b.w) << 16);
    return r.v;
}

// LDS-only barrier: global prefetch stays in flight
__device__ __forceinline__ void bar() {
    asm volatile("s_waitcnt lgkmcnt(0)" ::: "memory");
    __builtin_amdgcn_s_barrier();
    asm volatile("" ::: "memory");
}

#define MFMA(A, B, C) __builtin_amdgcn_mfma_f32_16x16x32_bf16((A), (B), (C), 0, 0, 0)

__global__ __launch_bounds__(NTHREADS, 2) void gru_persist(
    const float* __restrict__ x, const float* __restrict__ wih, const float* __restrict__ whh,
    const float* __restrict__ bih, const float* __restrict__ bhh,
    const float* __restrict__ h2ow, const float* __restrict__ h2ob_p,
    const float* __restrict__ w1w, const float* __restrict__ w1b_p,
    const float* __restrict__ w2w, const float* __restrict__ w2b_p,
    float* __restrict__ out)
{
    __shared__ Smem S;
    const int tid = threadIdx.x;
    const int l = tid & 63;
    const int w = tid >> 6;
    const int g = l >> 4;
    const int cl = l & 15;
    const int b0 = blockIdx.x * RW;

    // ---- zero LDS (K-pad lanes of frags must be 0; rest hygiene) ----
    for (int i = tid; i < (int)(sizeof(Smem) / 4); i += NTHREADS) ((u32*)&S)[i] = 0u;

    // ---- weights: global -> persistent registers (no LDS staging) ----
    const bf16x8 zf = {0, 0, 0, 0, 0, 0, 0, 0};
    bf16x8 wihR[3], whhR[3][4], headR[4];
#pragma unroll
    for (int s = 0; s < 3; ++s) {
        const int tw = w + 8 * s;                    // gate col-tile (r: 0-7, z: 8-15, n: 16-23)
        wihR[s] = (l < 48) ? ldfrag(wih + (16 * tw + cl) * NI + 8 * g) : zf;
#pragma unroll
        for (int kt = 0; kt < 4; ++kt)
            whhR[s][kt] = ldfrag(whh + (16 * tw + cl) * NH + 32 * kt + 8 * g);
    }
    if (w < 2) {                                     // W1 tile w (cols 16-23 only on w1/cl<8)
#pragma unroll
        for (int kt = 0; kt < 4; ++kt)
            headR[kt] = (w == 0 || cl < 8) ? ldfrag(w1w + (16 * w + cl) * NH + 32 * kt + 8 * g) : zf;
    } else if (w == 2) {                             // h2o as B-frag col 0
#pragma unroll
        for (int kt = 0; kt < 4; ++kt)
            headR[kt] = (cl == 0) ? ldfrag(h2ow + 32 * kt + 8 * g) : zf;
    } else {                                         // W2 tiles 0,1 (K=24)
        headR[0] = (g < 3) ? ldfrag(w2w + cl * NI + 8 * g) : zf;
        headR[1] = (g < 3 && cl < 8) ? ldfrag(w2w + (16 + cl) * NI + 8 * g) : zf;
        headR[2] = zf;
        headR[3] = zf;
    }

    // per-lane constants
    const float bR  = bih[w * 16 + cl] + bhh[w * 16 + cl];
    const float bZ  = bih[128 + w * 16 + cl] + bhh[128 + w * 16 + cl];
    const float bxN = bih[256 + w * 16 + cl];
    const float bhN = bhh[256 + w * 16 + cl];
    const float w1bias = (w == 0) ? w1b_p[cl] : ((w == 1 && cl < 8) ? w1b_p[16 + cl] : 0.0f);
    const float w2b0 = w2b_p[cl];
    const float w2b1 = (cl < 8) ? w2b_p[16 + cl] : 0.0f;
    const float h2ob = h2ob_p[0];

    // h ownership + phi-swizzle (phi(p) = p + ((p>>3)&1) + 2*(p>>4))
    const int ktH = w >> 1;
    const int cc = (2 * w + (cl >> 3)) & 3;
    const int hsB0 = 4 * g + 16 * cc + (g >> 1) + 2 * cc;
    const int eH = cl & 7;
    const int hsl = l + ((l >> 3) & 1) + 2 * (l >> 4);
    float h_reg[4] = {0.f, 0.f, 0.f, 0.f};

    bar();   // LDS zeroed

    // x(t=0) staging (8 rows x 48 cols)
    if (tid < 96) {
        const float* src = x + ((size_t)(b0 + tid / 12) * TSTEPS) * 48 + (tid % 12) * 4;
        *(float4*)&S.xt[0][tid / 12][(tid % 12) * 4] = *(const float4*)src;
    }
    bar();

    // build c(0)=h1(0) and x(0) fragments (rows 0-7)
    if (tid < 192) {
        int rr = tid & 7, j = tid >> 3;
        float h1 = S.xt[0][rr][j];
        float h2 = S.xt[0][rr][24 + j];
        int lane = rr + (j >> 3) * 16, el = j & 7;
        u16 hi = f2bf(h1);
        S.chi[lane][el] = hi;  S.clo[lane][el] = f2bf(h1 - bf2f(hi));
        S.x1hi[0][lane][el] = hi;
        S.x2hi[0][lane][el] = f2bf(h2);
    }
    float4 xfA, xfB;
    if (tid < 96) {
        const float* src = x + ((size_t)(b0 + tid / 12) * TSTEPS + 1) * 48 + (tid % 12) * 4;
        xfA = *(const float4*)src;
    }
    // gh(0) carry: h(-1)=0 -> biases only
    f32x4 gR = {bR, bR, bR, bR};
    f32x4 gZ = {bZ, bZ, bZ, bZ};
    f32x4 gN = {bhN, bhN, bhN, bhN};
    __syncthreads();

    for (int t = 0; t < TSTEPS; ++t) {
        const int cb = t & 1;
        const int nxt = (t + 1) & 1;
        const bool ld2 = (tid < 96) && (t + 2 < TSTEPS);
        const bool st1 = (tid < 96) && (t + 1 < TSTEPS);
        if (ld2) {
            const float* src = x + ((size_t)(b0 + tid / 12) * TSTEPS + (t + 2)) * 48 + (tid % 12) * 4;
            xfB = *(const float4*)src;
        }
        // ---- P1: finish gates with c(t); gR/gZ/gN carry h-part from prev tail ----
        f32x4 aN = {bxN, bxN, bxN, bxN};
        {
            bf16x8 cH = *(const bf16x8*)&S.chi[l][0];
            bf16x8 cL = *(const bf16x8*)&S.clo[l][0];
            gR = MFMA(cH, wihR[0], gR);  gR = MFMA(cL, wihR[0], gR);
            gZ = MFMA(cH, wihR[1], gZ);  gZ = MFMA(cL, wihR[1], gZ);
            aN = MFMA(cH, wihR[2], aN);  aN = MFMA(cL, wihR[2], aN);
        }
        if (w == 4 || w == 5) {     // s1/s2 x-parts from x(t) frags (buffer cb)
            bf16x8 aH = (w == 4) ? *(const bf16x8*)&S.x1hi[cb][l][0]
                                 : *(const bf16x8*)&S.x2hi[cb][l][0];
            f32x4 a0 = {w2b0, w2b0, w2b0, w2b0};
            f32x4 a1v = {w2b1, w2b1, w2b1, w2b1};
            a0 = MFMA(aH, headR[0], a0);
            a1v = MFMA(aH, headR[1], a1v);
            float(*ex)[26] = (w == 4) ? S.exs1 : S.exs2;
#pragma unroll
            for (int i = 0; i < 4; ++i) ex[4 * g + i][cl] = a0[i];
            if (cl < 8) {
#pragma unroll
                for (int i = 0; i < 4; ++i) ex[4 * g + i][16 + cl] = a1v[i];
            }
        }
        // gates; h_old in registers; store h(t) (hi only) to buffer cb
#pragma unroll
        for (int i = 0; i < 4; ++i) {
            float r = sigm(gR[i]);
            float z = sigm(gZ[i]);
            float n = tanhf_(aN[i] + r * gN[i]);
            float hv = (1.0f - z) * n + z * h_reg[i];
            h_reg[i] = hv;
            S.hhi[cb][ktH][hsB0 + i][eH] = f2bf(hv);
        }
        // x(t+1): stage to xt + build x-frags (buffer nxt) from registers
        if (st1) {
            *(float4*)&S.xt[nxt][tid / 12][(tid % 12) * 4] = xfA;
            int row = tid / 12, col0 = (tid % 12) * 4;
            int jj0 = (col0 < 24) ? col0 : col0 - 24;
            int lane = row + (jj0 >> 3) * 16, el0 = jj0 & 7;   // el0 in {0,4}
            u16* dst = (col0 < 24) ? &S.x1hi[nxt][lane][el0] : &S.x2hi[nxt][lane][el0];
            u32 lo = (u32)f2bf(xfA.x) | ((u32)f2bf(xfA.y) << 16);
            u32 hi = (u32)f2bf(xfA.z) | ((u32)f2bf(xfA.w) << 16);
            *(u32*)dst = lo;
            *(u32*)(dst + 2) = hi;
        }
        xfA = xfB;
        bar(); // B3: h(t), x(t+1) frags, exs visible
        // ---- tail: gh(t+1) on all waves (hi only); heads ride the same registers ----
        gR = (f32x4){bR, bR, bR, bR};
        gZ = (f32x4){bZ, bZ, bZ, bZ};
        gN = (f32x4){bhN, bhN, bhN, bhN};
        f32x4 hacc = (w < 2) ? (f32x4){w1bias, w1bias, w1bias, w1bias}
                             : (f32x4){0.f, 0.f, 0.f, 0.f};
#pragma unroll
        for (int kt = 0; kt < 4; ++kt) {
            bf16x8 hH = *(const bf16x8*)&S.hhi[cb][kt][hsl][0];
            gR = MFMA(hH, whhR[0][kt], gR);
            gZ = MFMA(hH, whhR[1][kt], gZ);
            gN = MFMA(hH, whhR[2][kt], gN);
            if (w < 3) hacc = MFMA(hH, headR[kt], hacc);
        }
        if (w < 2) {
            int col = w * 16 + cl;
            if (col < 24) {
#pragma unroll
                for (int i = 0; i < 4; ++i) S.exw1h[4 * g + i][col] = hacc[i];
            }
        } else if (w == 2) {
            if (cl == 0 && g < 2) {      // rows 0-7 only (rows 8-15 are dead lanes)
#pragma unroll
                for (int i = 0; i < 4; ++i)
                    out[(size_t)(b0 + 4 * g + i) * TSTEPS + t] = tanhf_(hacc[i] + h2ob);
            }
        }
        bar(); // B4: exw1h visible
        // ---- phase 3 (192 thr, rows 0-7): a(t+1) -> c(t+1) frags ----
        if (tid < 192) {
            int rr = tid & 7, j = tid >> 3;
            float v = S.exw1h[rr][j];
            float e1 = fexp(tanhf_(v + S.exs1[rr][j]));
            float e2 = fexp(tanhf_(v + S.exs2[rr][j]));
            float inv = frcp(e1 + e2);
            float h1 = S.xt[nxt][rr][j];
            float h2 = S.xt[nxt][rr][24 + j];
            float cv = (e1 * inv) * h1 + (e2 * inv) * h2;
            int lane = rr + (j >> 3) * 16, el = j & 7;
            u16 hi = f2bf(cv);
            S.chi[lane][el] = hi;
            S.clo[lane][el] = f2bf(cv - bf2f(hi));
        }
        bar(); // B5: c frags ready for next P1
    }
}

extern "C" void kernel_launch(void* const* d_in, const int* in_sizes, int n_in,
                              void* d_out, int out_size, void* d_ws, size_t ws_size,
                              hipStream_t stream) {
    const float* x    = (const float*)d_in[0];
    const float* wih  = (const float*)d_in[1];
    const float* whh  = (const float*)d_in[2];
    const float* bih  = (const float*)d_in[3];
    const float* bhh  = (const float*)d_in[4];
    const float* h2ow = (const float*)d_in[5];
    const float* h2ob = (const float*)d_in[6];
    const float* w1w  = (const float*)d_in[7];
    const float* w1b  = (const float*)d_in[8];
    const float* w2w  = (const float*)d_in[9];
    const float* w2b  = (const float*)d_in[10];
    float* out = (float*)d_out;

    gru_persist<<<NWG, NTHREADS, 0, stream>>>(x, wih, whh, bih, bhh,
                                              h2ow, h2ob, w1w, w1b, w2w, w2b, out);
}

// Round 10
// 737.173 us; speedup vs baseline: 2.0368x; 1.1096x over previous
//
#include <hip/hip_runtime.h>

#define TSTEPS 336
#define NI 24
#define NH 128
#define RW 16          // rows per WG: two 8-row pipelined chains
#define NTHREADS 512
#define NWG 256        // 4096 / RW

typedef __attribute__((ext_vector_type(8))) short bf16x8;
typedef __attribute__((ext_vector_type(4))) float f32x4;
typedef unsigned short u16;
typedef unsigned int u32;

struct __align__(16) Smem {
    u16 hhi[4][72][8];                  // 4608  h frags (hi only), phi-swizzled; rows 0-7=alpha, 8-15=beta
    u16 chi[64][8], clo[64][8];         // 2048  c frags, rows split by block
    u16 x1hi[64][8], x2hi[64][8];       // 2048  x frags (hi only)
    float xt[2][16][52];                // 6656  x staging, parity buffers
    float exw1h[16][26], exs1[16][26], exs2[16][26]; // 4992
};                                      // 20352 B
static_assert(sizeof(Smem) <= 65536, "LDS overflow");

__device__ __forceinline__ u16 f2bf(float f) {
    u32 u = __float_as_uint(f);
    return (u16)((u + 0x7FFFu + ((u >> 16) & 1u)) >> 16);
}
__device__ __forceinline__ float bf2f(u16 h) { return __uint_as_float(((u32)h) << 16); }
__device__ __forceinline__ float frcp(float x) { return __builtin_amdgcn_rcpf(x); }
__device__ __forceinline__ float fex2(float x) { return __builtin_amdgcn_exp2f(x); }
__device__ __forceinline__ float sigm(float x) { return frcp(1.0f + fex2(-1.4426950408889634f * x)); }
__device__ __forceinline__ float tanhf_(float x) { return 1.0f - 2.0f * frcp(1.0f + fex2(2.8853900817779268f * x)); }
__device__ __forceinline__ float fexp(float x) { return fex2(1.4426950408889634f * x); }

__device__ __forceinline__ bf16x8 ldfrag(const float* __restrict__ p) {
    float4 a = *(const float4*)p;
    float4 b = *(const float4*)(p + 4);
    union { u32 u[4]; bf16x8 v; } r;
    r.u[0] = (u32)f2bf(a.x) | ((u32)f2bf(a.y) << 16);
    r.u[1] = (u32)f2bf(a.z) | ((u32)f2bf(a.w) << 16);
    r.u[2] = (u32)f2bf(b.x) | ((u32)f2bf(b.y) << 16);
    r.u[3] = (u32)f2bf(b.z) | ((u32)f2bf(b.w) << 16);
    return r.v;
}

__device__ __forceinline__ void bar() {
    asm volatile("s_waitcnt lgkmcnt(0)" ::: "memory");
    __builtin_amdgcn_s_barrier();
    asm volatile("" ::: "memory");
}

#define MFMA(A, B, C) __builtin_amdgcn_mfma_f32_16x16x32_bf16((A), (B), (C), 0, 0, 0)

// ---- stage A(block b, step t): finish gates with c(t), update h, store h frags ----
#define DO_A(b, gRb, gZb, gNb, hb)                                              \
{                                                                               \
    f32x4 aN = {bxN, bxN, bxN, bxN};                                            \
    bf16x8 cH = *(const bf16x8*)&S.chi[l][0];                                   \
    bf16x8 cL = *(const bf16x8*)&S.clo[l][0];                                   \
    gRb = MFMA(cH, wihR[0], gRb);  gRb = MFMA(cL, wihR[0], gRb);                \
    gZb = MFMA(cH, wihR[1], gZb);  gZb = MFMA(cL, wihR[1], gZb);                \
    aN  = MFMA(cH, wihR[2], aN);   aN  = MFMA(cL, wihR[2], aN);                 \
    if (w == 4 || w == 5) {                                                     \
        bf16x8 aH = (w == 4) ? *(const bf16x8*)&S.x1hi[l][0]                    \
                             : *(const bf16x8*)&S.x2hi[l][0];                   \
        f32x4 a0 = {w2b0, w2b0, w2b0, w2b0};                                    \
        f32x4 a1v = {w2b1, w2b1, w2b1, w2b1};                                   \
        a0 = MFMA(aH, headR[0], a0);                                            \
        a1v = MFMA(aH, headR[1], a1v);                                          \
        float(*ex)[26] = (w == 4) ? S.exs1 : S.exs2;                            \
        if ((g >> 1) == (b)) {                                                  \
            _Pragma("unroll")                                                   \
            for (int i = 0; i < 4; ++i) ex[4 * g + i][cl] = a0[i];              \
            if (cl < 8) {                                                       \
                _Pragma("unroll")                                               \
                for (int i = 0; i < 4; ++i) ex[4 * g + i][16 + cl] = a1v[i];    \
            }                                                                   \
        }                                                                       \
    }                                                                           \
    _Pragma("unroll")                                                           \
    for (int i = 0; i < 4; ++i) {                                               \
        float r = sigm(gRb[i]);                                                 \
        float z = sigm(gZb[i]);                                                 \
        float n = tanhf_(aN[i] + r * gNb[i]);                                   \
        hb[i] = (1.0f - z) * n + z * hb[i];                                     \
    }                                                                           \
    if ((g >> 1) == (b)) {                                                      \
        _Pragma("unroll")                                                       \
        for (int i = 0; i < 4; ++i)                                             \
            S.hhi[ktH][hsB0 + i][eH] = f2bf(hb[i]);                             \
    }                                                                           \
}

// ---- stage B(block b, step tt): gh(tt+1) + heads off h(tt) ----
#define DO_B(b, gRb, gZb, gNb, tt)                                              \
{                                                                               \
    gRb = (f32x4){bR, bR, bR, bR};                                              \
    gZb = (f32x4){bZ, bZ, bZ, bZ};                                              \
    gNb = (f32x4){bhN, bhN, bhN, bhN};                                          \
    f32x4 hacc = (w < 2) ? (f32x4){w1bias, w1bias, w1bias, w1bias}              \
                         : (f32x4){0.f, 0.f, 0.f, 0.f};                         \
    _Pragma("unroll")                                                           \
    for (int kt = 0; kt < 4; ++kt) {                                            \
        bf16x8 hH = *(const bf16x8*)&S.hhi[kt][hsl][0];                         \
        gRb = MFMA(hH, whhR[0][kt], gRb);                                       \
        gZb = MFMA(hH, whhR[1][kt], gZb);                                       \
        gNb = MFMA(hH, whhR[2][kt], gNb);                                       \
        if (w < 3) hacc = MFMA(hH, headR[kt], hacc);                            \
    }                                                                           \
    if (w < 2) {                                                                \
        int col = w * 16 + cl;                                                  \
        if (col < 24 && (g >> 1) == (b)) {                                      \
            _Pragma("unroll")                                                   \
            for (int i = 0; i < 4; ++i) S.exw1h[4 * g + i][col] = hacc[i];      \
        }                                                                       \
    } else if (w == 2) {                                                        \
        if (cl == 0 && (g >> 1) == (b)) {                                       \
            _Pragma("unroll")                                                   \
            for (int i = 0; i < 4; ++i)                                         \
                out[(size_t)(b0 + 4 * g + i) * TSTEPS + (tt)] = tanhf_(hacc[i] + h2ob); \
        }                                                                       \
    }                                                                           \
}

// ---- stage C(block b, parity par): attention -> c/x frags for next step ----
#define DO_C(b, par)                                                            \
{                                                                               \
    if (tid < 192) {                                                            \
        int rr = (b) * 8 + (tid & 7), j = tid >> 3;                             \
        float v = S.exw1h[rr][j];                                               \
        float e1 = fexp(tanhf_(v + S.exs1[rr][j]));                             \
        float e2 = fexp(tanhf_(v + S.exs2[rr][j]));                             \
        float inv = frcp(e1 + e2);                                              \
        float h1 = S.xt[par][rr][j];                                            \
        float h2 = S.xt[par][rr][24 + j];                                       \
        float cv = (e1 * inv) * h1 + (e2 * inv) * h2;                           \
        int lane = rr + (j >> 3) * 16, el = j & 7;                              \
        u16 hi = f2bf(cv);                                                      \
        S.chi[lane][el] = hi;                                                   \
        S.clo[lane][el] = f2bf(cv - bf2f(hi));                                  \
        S.x1hi[lane][el] = f2bf(h1);                                            \
        S.x2hi[lane][el] = f2bf(h2);                                            \
    }                                                                           \
}

__global__ __launch_bounds__(NTHREADS, 2) void gru_persist(
    const float* __restrict__ x, const float* __restrict__ wih, const float* __restrict__ whh,
    const float* __restrict__ bih, const float* __restrict__ bhh,
    const float* __restrict__ h2ow, const float* __restrict__ h2ob_p,
    const float* __restrict__ w1w, const float* __restrict__ w1b_p,
    const float* __restrict__ w2w, const float* __restrict__ w2b_p,
    float* __restrict__ out)
{
    __shared__ Smem S;
    const int tid = threadIdx.x;
    const int l = tid & 63;
    const int w = tid >> 6;
    const int g = l >> 4;
    const int cl = l & 15;
    const int b0 = blockIdx.x * RW;

    for (int i = tid; i < (int)(sizeof(Smem) / 4); i += NTHREADS) ((u32*)&S)[i] = 0u;

    // ---- weights: global -> persistent registers ----
    const bf16x8 zf = {0, 0, 0, 0, 0, 0, 0, 0};
    bf16x8 wihR[3], whhR[3][4], headR[4];
#pragma unroll
    for (int s = 0; s < 3; ++s) {
        const int tw = w + 8 * s;
        wihR[s] = (l < 48) ? ldfrag(wih + (16 * tw + cl) * NI + 8 * g) : zf;
#pragma unroll
        for (int kt = 0; kt < 4; ++kt)
            whhR[s][kt] = ldfrag(whh + (16 * tw + cl) * NH + 32 * kt + 8 * g);
    }
    if (w < 2) {
#pragma unroll
        for (int kt = 0; kt < 4; ++kt)
            headR[kt] = (w == 0 || cl < 8) ? ldfrag(w1w + (16 * w + cl) * NH + 32 * kt + 8 * g) : zf;
    } else if (w == 2) {
#pragma unroll
        for (int kt = 0; kt < 4; ++kt)
            headR[kt] = (cl == 0) ? ldfrag(h2ow + 32 * kt + 8 * g) : zf;
    } else {
        headR[0] = (g < 3) ? ldfrag(w2w + cl * NI + 8 * g) : zf;
        headR[1] = (g < 3 && cl < 8) ? ldfrag(w2w + (16 + cl) * NI + 8 * g) : zf;
        headR[2] = zf;
        headR[3] = zf;
    }

    const float bR  = bih[w * 16 + cl] + bhh[w * 16 + cl];
    const float bZ  = bih[128 + w * 16 + cl] + bhh[128 + w * 16 + cl];
    const float bxN = bih[256 + w * 16 + cl];
    const float bhN = bhh[256 + w * 16 + cl];
    const float w1bias = (w == 0) ? w1b_p[cl] : ((w == 1 && cl < 8) ? w1b_p[16 + cl] : 0.0f);
    const float w2b0 = w2b_p[cl];
    const float w2b1 = (cl < 8) ? w2b_p[16 + cl] : 0.0f;
    const float h2ob = h2ob_p[0];

    // h frag addressing (phi(p) = p + ((p>>3)&1) + 2*(p>>4))
    const int ktH = w >> 1;
    const int cc = (2 * w + (cl >> 3)) & 3;
    const int hsB0 = 4 * g + 16 * cc + (g >> 1) + 2 * cc;
    const int eH = cl & 7;
    const int hsl = l + ((l >> 3) & 1) + 2 * (l >> 4);

    float h0[4] = {0.f, 0.f, 0.f, 0.f};
    float h1[4] = {0.f, 0.f, 0.f, 0.f};

    bar();   // LDS zeroed

    // x(0) staging: 16 rows x 48 floats
    if (tid < 192) {
        const float* src = x + ((size_t)(b0 + tid / 12) * TSTEPS) * 48 + (tid % 12) * 4;
        *(float4*)&S.xt[0][tid / 12][(tid % 12) * 4] = *(const float4*)src;
    }
    bar();

    // c(0)=h1(0), x(0) frags for both blocks (rows 0-15)
    if (tid < 384) {
        int rr = tid & 15, j = tid >> 4;
        float xh1 = S.xt[0][rr][j];
        float xh2 = S.xt[0][rr][24 + j];
        int lane = rr + (j >> 3) * 16, el = j & 7;
        u16 hi = f2bf(xh1);
        S.chi[lane][el] = hi;  S.clo[lane][el] = f2bf(xh1 - bf2f(hi));
        S.x1hi[lane][el] = hi;
        S.x2hi[lane][el] = f2bf(xh2);
    }
    float4 xfA, xfB;
    if (tid < 192) {
        const float* src = x + ((size_t)(b0 + tid / 12) * TSTEPS + 1) * 48 + (tid % 12) * 4;
        xfA = *(const float4*)src;
    }
    // gh(0) carries = biases (h(-1)=0), both blocks
    f32x4 gR0 = {bR, bR, bR, bR}, gZ0 = {bZ, bZ, bZ, bZ}, gN0 = {bhN, bhN, bhN, bhN};
    f32x4 gR1 = gR0, gZ1 = gZ0, gN1 = gN0;
    __syncthreads();

    for (int t = 0; t <= TSTEPS; ++t) {
        const int nb = (t + 1) & 1;
        if (tid < 192 && t + 2 < TSTEPS) {   // prefetch x(t+2); in flight across phases
            const float* src = x + ((size_t)(b0 + tid / 12) * TSTEPS + (t + 2)) * 48 + (tid % 12) * 4;
            xfB = *(const float4*)src;
        }
        // ---- phase X: A_alpha(t) || B_beta(t-1) ----
        if (t < TSTEPS) DO_A(0, gR0, gZ0, gN0, h0);
        if (t >= 1)     DO_B(1, gR1, gZ1, gN1, t - 1);
        if (tid < 192 && t + 1 < TSTEPS)
            *(float4*)&S.xt[nb][tid / 12][(tid % 12) * 4] = xfA;
        xfA = xfB;
        bar();
        // ---- phase Y: B_alpha(t) || C_beta(t-1) -> c_beta(t) ----
        if (t < TSTEPS) DO_B(0, gR0, gZ0, gN0, t);
        if (t >= 1 && t < TSTEPS) DO_C(1, t & 1);
        bar();
        // ---- phase Z: C_alpha(t) -> c_alpha(t+1) || A_beta(t) ----
        if (t < TSTEPS - 1) DO_C(0, nb);
        if (t < TSTEPS)     DO_A(1, gR1, gZ1, gN1, h1);
        bar();
    }
}

extern "C" void kernel_launch(void* const* d_in, const int* in_sizes, int n_in,
                              void* d_out, int out_size, void* d_ws, size_t ws_size,
                              hipStream_t stream) {
    const float* x    = (const float*)d_in[0];
    const float* wih  = (const float*)d_in[1];
    const float* whh  = (const float*)d_in[2];
    const float* bih  = (const float*)d_in[3];
    const float* bhh  = (const float*)d_in[4];
    const float* h2ow = (const float*)d_in[5];
    const float* h2ob = (const float*)d_in[6];
    const float* w1w  = (const float*)d_in[7];
    const float* w1b  = (const float*)d_in[8];
    const float* w2w  = (const float*)d_in[9];
    const float* w2b  = (const float*)d_in[10];
    float* out = (float*)d_out;

    gru_persist<<<NWG, NTHREADS, 0, stream>>>(x, wih, whh, bih, bhh,
                                              h2ow, h2ob, w1w, w1b, w2w, w2b, out);
}

// Round 11
// 664.178 us; speedup vs baseline: 2.2606x; 1.1099x over previous
//
#include <hip/hip_runtime.h>

#define TSTEPS 336
#define NI 24
#define NH 128
#define RW 8           // batch rows per workgroup
#define NTHREADS 256   // 4 waves; 2 WGs/CU co-resident (420 of 512 VGPRs used)
#define NWG 512        // 4096 / RW

typedef __attribute__((ext_vector_type(8))) short bf16x8;
typedef __attribute__((ext_vector_type(4))) float f32x4;
typedef unsigned short u16;
typedef unsigned int u32;

struct __align__(16) Smem {
    u16 hhi[4][72][8];                  // 4608  h frags (hi only), phi-swizzled slots
    u16 chi[64][8], clo[64][8];         // 2048  c hi/lo A-frags (rows 8-15 & K-pad stay zero)
    u16 x1hi[64][8], x2hi[64][8];       // 2048  x A-frags (hi only)
    float xt[2][8][52];                 // 3328  x staging, padded rows
    float exw1h[16][26], exs1[16][26], exs2[16][26]; // 4992
};                                      // 17024 B -> 2 WG/CU
static_assert(sizeof(Smem) <= 65536, "LDS overflow");

__device__ __forceinline__ u16 f2bf(float f) {
    u32 u = __float_as_uint(f);
    return (u16)((u + 0x7FFFu + ((u >> 16) & 1u)) >> 16);
}
__device__ __forceinline__ float bf2f(u16 h) { return __uint_as_float(((u32)h) << 16); }
__device__ __forceinline__ float frcp(float x) { return __builtin_amdgcn_rcpf(x); }
__device__ __forceinline__ float fex2(float x) { return __builtin_amdgcn_exp2f(x); }
__device__ __forceinline__ float sigm(float x) { return frcp(1.0f + fex2(-1.4426950408889634f * x)); }
__device__ __forceinline__ float tanhf_(float x) { return 1.0f - 2.0f * frcp(1.0f + fex2(2.8853900817779268f * x)); }
__device__ __forceinline__ float fexp(float x) { return fex2(1.4426950408889634f * x); }

// pack 8 consecutive f32 -> bf16x8 (RNE)
__device__ __forceinline__ bf16x8 ldfrag(const float* __restrict__ p) {
    float4 a = *(const float4*)p;
    float4 b = *(const float4*)(p + 4);
    union { u32 u[4]; bf16x8 v; } r;
    r.u[0] = (u32)f2bf(a.x) | ((u32)f2bf(a.y) << 16);
    r.u[1] = (u32)f2bf(a.z) | ((u32)f2bf(a.w) << 16);
    r.u[2] = (u32)f2bf(b.x) | ((u32)f2bf(b.y) << 16);
    r.u[3] = (u32)f2bf(b.z) | ((u32)f2bf(b.w) << 16);
    return r.v;
}

// LDS-only barrier: global prefetch stays in flight
__device__ __forceinline__ void bar() {
    asm volatile("s_waitcnt lgkmcnt(0)" ::: "memory");
    __builtin_amdgcn_s_barrier();
    asm volatile("" ::: "memory");
}

#define MFMA(A, B, C) __builtin_amdgcn_mfma_f32_16x16x32_bf16((A), (B), (C), 0, 0, 0)

__global__ __launch_bounds__(NTHREADS, 2) void gru_persist(
    const float* __restrict__ x, const float* __restrict__ wih, const float* __restrict__ whh,
    const float* __restrict__ bih, const float* __restrict__ bhh,
    const float* __restrict__ h2ow, const float* __restrict__ h2ob_p,
    const float* __restrict__ w1w, const float* __restrict__ w1b_p,
    const float* __restrict__ w2w, const float* __restrict__ w2b_p,
    float* __restrict__ out)
{
    __shared__ Smem S;
    const int tid = threadIdx.x;
    const int l = tid & 63;
    const int w = tid >> 6;      // wave 0..3
    const int g = l >> 4;
    const int cl = l & 15;
    const int b0 = blockIdx.x * RW;

    for (int i = tid; i < (int)(sizeof(Smem) / 4); i += NTHREADS) ((u32*)&S)[i] = 0u;

    // ---- weights -> persistent registers; wave w owns gate col-groups (w) and (w+4) ----
    const bf16x8 zf = {0, 0, 0, 0, 0, 0, 0, 0};
    bf16x8 wihR[3][2], whhR[3][2][4], headR[4];
#pragma unroll
    for (int s = 0; s < 3; ++s) {
#pragma unroll
        for (int d = 0; d < 2; ++d) {
            const int tw = 8 * s + w + 4 * d;        // tile 0..23
            wihR[s][d] = (l < 48) ? ldfrag(wih + (16 * tw + cl) * NI + 8 * g) : zf;
#pragma unroll
            for (int kt = 0; kt < 4; ++kt)
                whhR[s][d][kt] = ldfrag(whh + (16 * tw + cl) * NH + 32 * kt + 8 * g);
        }
    }
    if (w == 0) {
#pragma unroll
        for (int kt = 0; kt < 4; ++kt) headR[kt] = ldfrag(w1w + cl * NH + 32 * kt + 8 * g);
    } else if (w == 1) {
#pragma unroll
        for (int kt = 0; kt < 4; ++kt)
            headR[kt] = (cl < 8) ? ldfrag(w1w + (16 + cl) * NH + 32 * kt + 8 * g) : zf;
    } else if (w == 2) {
#pragma unroll
        for (int kt = 0; kt < 4; ++kt)
            headR[kt] = (cl == 0) ? ldfrag(h2ow + 32 * kt + 8 * g) : zf;
    } else {
        headR[0] = (g < 3) ? ldfrag(w2w + cl * NI + 8 * g) : zf;
        headR[1] = (g < 3 && cl < 8) ? ldfrag(w2w + (16 + cl) * NI + 8 * g) : zf;
        headR[2] = zf;
        headR[3] = zf;
    }

    // per-lane constants (two unit-groups u0 = 16w+cl, u1 = u0+64)
    const int u0 = 16 * w + cl, u1 = u0 + 64;
    const float bR0 = bih[u0] + bhh[u0],             bR1 = bih[u1] + bhh[u1];
    const float bZ0 = bih[128 + u0] + bhh[128 + u0], bZ1 = bih[128 + u1] + bhh[128 + u1];
    const float bxN0 = bih[256 + u0],  bxN1 = bih[256 + u1];
    const float bhN0 = bhh[256 + u0],  bhN1 = bhh[256 + u1];
    const float w1bias = (w == 0) ? w1b_p[cl] : ((w == 1 && cl < 8) ? w1b_p[16 + cl] : 0.0f);
    const float w2b0 = w2b_p[cl];
    const float w2b1 = (cl < 8) ? w2b_p[16 + cl] : 0.0f;
    const float h2ob = h2ob_p[0];

    // h frag addressing (phi(p) = p + ((p>>3)&1) + 2*(p>>4)); d=1 shifts kt by +2, cc unchanged
    const int ktH0 = w >> 1, ktH1 = ktH0 + 2;
    const int cc = (2 * w + (cl >> 3)) & 3;
    const int hsB0 = 4 * g + 16 * cc + (g >> 1) + 2 * cc;
    const int eH = cl & 7;
    const int hsl = l + ((l >> 3) & 1) + 2 * (l >> 4);
    float h_reg0[4] = {0.f, 0.f, 0.f, 0.f};
    float h_reg1[4] = {0.f, 0.f, 0.f, 0.f};

    bar();   // LDS zeroed

    // x(0) staging (8 rows x 48 floats)
    if (tid < 96) {
        const float* src = x + ((size_t)(b0 + tid / 12) * TSTEPS) * 48 + (tid % 12) * 4;
        *(float4*)&S.xt[0][tid / 12][(tid % 12) * 4] = *(const float4*)src;
    }
    bar();

    // c(0)=h1(0) and x(0) fragments (rows 0-7)
    if (tid < 192) {
        int rr = tid & 7, j = tid >> 3;
        float h1 = S.xt[0][rr][j];
        float h2 = S.xt[0][rr][24 + j];
        int lane = rr + (j >> 3) * 16, el = j & 7;
        u16 hi = f2bf(h1);
        S.chi[lane][el] = hi;  S.clo[lane][el] = f2bf(h1 - bf2f(hi));
        S.x1hi[lane][el] = hi;
        S.x2hi[lane][el] = f2bf(h2);
    }
    float4 xfA, xfB;
    if (tid < 96) {
        const float* src = x + ((size_t)(b0 + tid / 12) * TSTEPS + 1) * 48 + (tid % 12) * 4;
        xfA = *(const float4*)src;
    }
    // gh(0) carries = biases (h(-1)=0)
    f32x4 gR0 = {bR0, bR0, bR0, bR0}, gZ0 = {bZ0, bZ0, bZ0, bZ0}, gN0 = {bhN0, bhN0, bhN0, bhN0};
    f32x4 gR1 = {bR1, bR1, bR1, bR1}, gZ1 = {bZ1, bZ1, bZ1, bZ1}, gN1 = {bhN1, bhN1, bhN1, bhN1};
    __syncthreads();

    for (int t = 0; t < TSTEPS; ++t) {
        const int nxt = (t + 1) & 1;
        if (tid < 96 && t + 2 < TSTEPS) {   // 2-deep x prefetch
            const float* src = x + ((size_t)(b0 + tid / 12) * TSTEPS + (t + 2)) * 48 + (tid % 12) * 4;
            xfB = *(const float4*)src;
        }
        // ---- A: finish gates with c(t); update h; store h frags ----
        f32x4 aN0 = {bxN0, bxN0, bxN0, bxN0};
        f32x4 aN1 = {bxN1, bxN1, bxN1, bxN1};
        {
            bf16x8 cH = *(const bf16x8*)&S.chi[l][0];
            bf16x8 cL = *(const bf16x8*)&S.clo[l][0];
            gR0 = MFMA(cH, wihR[0][0], gR0);  gR0 = MFMA(cL, wihR[0][0], gR0);
            gR1 = MFMA(cH, wihR[0][1], gR1);  gR1 = MFMA(cL, wihR[0][1], gR1);
            gZ0 = MFMA(cH, wihR[1][0], gZ0);  gZ0 = MFMA(cL, wihR[1][0], gZ0);
            gZ1 = MFMA(cH, wihR[1][1], gZ1);  gZ1 = MFMA(cL, wihR[1][1], gZ1);
            aN0 = MFMA(cH, wihR[2][0], aN0);  aN0 = MFMA(cL, wihR[2][0], aN0);
            aN1 = MFMA(cH, wihR[2][1], aN1);  aN1 = MFMA(cL, wihR[2][1], aN1);
        }
        if (w == 3) {   // s1/s2 x-parts from x(t) frags
            bf16x8 aH1 = *(const bf16x8*)&S.x1hi[l][0];
            bf16x8 aH2 = *(const bf16x8*)&S.x2hi[l][0];
            f32x4 s1a = {w2b0, w2b0, w2b0, w2b0};
            f32x4 s1b = {w2b1, w2b1, w2b1, w2b1};
            f32x4 s2a = {w2b0, w2b0, w2b0, w2b0};
            f32x4 s2b = {w2b1, w2b1, w2b1, w2b1};
            s1a = MFMA(aH1, headR[0], s1a);
            s1b = MFMA(aH1, headR[1], s1b);
            s2a = MFMA(aH2, headR[0], s2a);
            s2b = MFMA(aH2, headR[1], s2b);
#pragma unroll
            for (int i = 0; i < 4; ++i) S.exs1[4 * g + i][cl] = s1a[i];
#pragma unroll
            for (int i = 0; i < 4; ++i) S.exs2[4 * g + i][cl] = s2a[i];
            if (cl < 8) {
#pragma unroll
                for (int i = 0; i < 4; ++i) S.exs1[4 * g + i][16 + cl] = s1b[i];
#pragma unroll
                for (int i = 0; i < 4; ++i) S.exs2[4 * g + i][16 + cl] = s2b[i];
            }
        }
        // gates for both unit-groups; h in fp32 registers; store hi frags
#pragma unroll
        for (int i = 0; i < 4; ++i) {
            float r = sigm(gR0[i]);
            float z = sigm(gZ0[i]);
            float n = tanhf_(aN0[i] + r * gN0[i]);
            float hv = (1.0f - z) * n + z * h_reg0[i];
            h_reg0[i] = hv;
            S.hhi[ktH0][hsB0 + i][eH] = f2bf(hv);
        }
#pragma unroll
        for (int i = 0; i < 4; ++i) {
            float r = sigm(gR1[i]);
            float z = sigm(gZ1[i]);
            float n = tanhf_(aN1[i] + r * gN1[i]);
            float hv = (1.0f - z) * n + z * h_reg1[i];
            h_reg1[i] = hv;
            S.hhi[ktH1][hsB0 + i][eH] = f2bf(hv);
        }
        if (tid < 96 && t + 1 < TSTEPS)
            *(float4*)&S.xt[nxt][tid / 12][(tid % 12) * 4] = xfA;
        xfA = xfB;
        bar(); // B3: h(t), x(t+1), exs visible
        // ---- B: gh(t+1) carries + heads off h(t) ----
        gR0 = (f32x4){bR0, bR0, bR0, bR0};  gR1 = (f32x4){bR1, bR1, bR1, bR1};
        gZ0 = (f32x4){bZ0, bZ0, bZ0, bZ0};  gZ1 = (f32x4){bZ1, bZ1, bZ1, bZ1};
        gN0 = (f32x4){bhN0, bhN0, bhN0, bhN0};  gN1 = (f32x4){bhN1, bhN1, bhN1, bhN1};
        f32x4 hacc = (w < 2) ? (f32x4){w1bias, w1bias, w1bias, w1bias}
                             : (f32x4){0.f, 0.f, 0.f, 0.f};
#pragma unroll
        for (int kt = 0; kt < 4; ++kt) {
            bf16x8 hH = *(const bf16x8*)&S.hhi[kt][hsl][0];
            gR0 = MFMA(hH, whhR[0][0][kt], gR0);
            gR1 = MFMA(hH, whhR[0][1][kt], gR1);
            gZ0 = MFMA(hH, whhR[1][0][kt], gZ0);
            gZ1 = MFMA(hH, whhR[1][1][kt], gZ1);
            gN0 = MFMA(hH, whhR[2][0][kt], gN0);
            gN1 = MFMA(hH, whhR[2][1][kt], gN1);
            if (w < 3) hacc = MFMA(hH, headR[kt], hacc);
        }
        if (w == 0) {
#pragma unroll
            for (int i = 0; i < 4; ++i) S.exw1h[4 * g + i][cl] = hacc[i];
        } else if (w == 1) {
            if (cl < 8) {
#pragma unroll
                for (int i = 0; i < 4; ++i) S.exw1h[4 * g + i][16 + cl] = hacc[i];
            }
        } else if (w == 2) {
            if (cl == 0 && g < 2) {   // rows 0-7 only
#pragma unroll
                for (int i = 0; i < 4; ++i)
                    out[(size_t)(b0 + 4 * g + i) * TSTEPS + t] = tanhf_(hacc[i] + h2ob);
            }
        }
        bar(); // B4: exw1h visible
        // ---- C: attention -> c(t+1) + x(t+1) frags (192 thr, rows 0-7) ----
        if (tid < 192) {
            int rr = tid & 7, j = tid >> 3;
            float v = S.exw1h[rr][j];
            float e1 = fexp(tanhf_(v + S.exs1[rr][j]));
            float e2 = fexp(tanhf_(v + S.exs2[rr][j]));
            float inv = frcp(e1 + e2);
            float h1 = S.xt[nxt][rr][j];
            float h2 = S.xt[nxt][rr][24 + j];
            float cv = (e1 * inv) * h1 + (e2 * inv) * h2;
            int lane = rr + (j >> 3) * 16, el = j & 7;
            u16 hi = f2bf(cv);
            S.chi[lane][el] = hi;
            S.clo[lane][el] = f2bf(cv - bf2f(hi));
            S.x1hi[lane][el] = f2bf(h1);
            S.x2hi[lane][el] = f2bf(h2);
        }
        bar(); // B5: c/x frags ready for next A
    }
}

extern "C" void kernel_launch(void* const* d_in, const int* in_sizes, int n_in,
                              void* d_out, int out_size, void* d_ws, size_t ws_size,
                              hipStream_t stream) {
    const float* x    = (const float*)d_in[0];
    const float* wih  = (const float*)d_in[1];
    const float* whh  = (const float*)d_in[2];
    const float* bih  = (const float*)d_in[3];
    const float* bhh  = (const float*)d_in[4];
    const float* h2ow = (const float*)d_in[5];
    const float* h2ob = (const float*)d_in[6];
    const float* w1w  = (const float*)d_in[7];
    const float* w1b  = (const float*)d_in[8];
    const float* w2w  = (const float*)d_in[9];
    const float* w2b  = (const float*)d_in[10];
    float* out = (float*)d_out;

    gru_persist<<<NWG, NTHREADS, 0, stream>>>(x, wih, whh, bih, bhh,
                                              h2ow, h2ob, w1w, w1b, w2w, w2b, out);
}

// Round 12
// 435.290 us; speedup vs baseline: 3.4493x; 1.5258x over previous
//
#include <hip/hip_runtime.h>

#define TSTEPS 336
#define NI 24
#define NH 128
#define RW 16          // batch rows per workgroup
#define NTHREADS 512
#define NWG 256        // 4096 / RW

typedef __attribute__((ext_vector_type(8))) short bf16x8;
typedef __attribute__((ext_vector_type(4))) float f32x4;
typedef unsigned short u16;
typedef unsigned int u32;

struct __align__(16) Smem {
    u16 hhi[4][72][8];                  // 4608  h frags (hi only), phi-swizzled slots
    u16 chi[64][8], clo[64][8];         // 2048  c hi/lo A-frags (K-pad lanes 48-63 stay zero)
    u16 x1hi[64][8], x2hi[64][8];       // 2048  x A-frags (hi only)
    float xt[2][16][52];                // 6656  x staging, padded rows
};                                      // 15360 B
static_assert(sizeof(Smem) <= 65536, "LDS overflow");

__device__ __forceinline__ u16 f2bf(float f) {
    u32 u = __float_as_uint(f);
    return (u16)((u + 0x7FFFu + ((u >> 16) & 1u)) >> 16);
}
__device__ __forceinline__ float bf2f(u16 h) { return __uint_as_float(((u32)h) << 16); }
__device__ __forceinline__ float frcp(float x) { return __builtin_amdgcn_rcpf(x); }
__device__ __forceinline__ float fex2(float x) { return __builtin_amdgcn_exp2f(x); }
__device__ __forceinline__ float sigm(float x) { return frcp(1.0f + fex2(-1.4426950408889634f * x)); }
__device__ __forceinline__ float tanhf_(float x) { return 1.0f - 2.0f * frcp(1.0f + fex2(2.8853900817779268f * x)); }
__device__ __forceinline__ float fexp(float x) { return fex2(1.4426950408889634f * x); }

// pack 8 consecutive f32 -> bf16x8 (RNE)
__device__ __forceinline__ bf16x8 ldfrag(const float* __restrict__ p) {
    float4 a = *(const float4*)p;
    float4 b = *(const float4*)(p + 4);
    union { u32 u[4]; bf16x8 v; } r;
    r.u[0] = (u32)f2bf(a.x) | ((u32)f2bf(a.y) << 16);
    r.u[1] = (u32)f2bf(a.z) | ((u32)f2bf(a.w) << 16);
    r.u[2] = (u32)f2bf(b.x) | ((u32)f2bf(b.y) << 16);
    r.u[3] = (u32)f2bf(b.z) | ((u32)f2bf(b.w) << 16);
    return r.v;
}

// LDS-only barrier: global prefetch stays in flight
__device__ __forceinline__ void bar() {
    asm volatile("s_waitcnt lgkmcnt(0)" ::: "memory");
    __builtin_amdgcn_s_barrier();
    asm volatile("" ::: "memory");
}

#define MFMA(A, B, C) __builtin_amdgcn_mfma_f32_16x16x32_bf16((A), (B), (C), 0, 0, 0)

__global__ __launch_bounds__(NTHREADS, 2) void gru_persist(
    const float* __restrict__ x, const float* __restrict__ wih, const float* __restrict__ whh,
    const float* __restrict__ bih, const float* __restrict__ bhh,
    const float* __restrict__ h2ow, const float* __restrict__ h2ob_p,
    const float* __restrict__ w1w, const float* __restrict__ w1b_p,
    const float* __restrict__ w2w, const float* __restrict__ w2b_p,
    float* __restrict__ out)
{
    __shared__ Smem S;
    const int tid = threadIdx.x;
    const int l = tid & 63;
    const int w = tid >> 6;      // wave 0..7
    const int g = l >> 4;
    const int cl = l & 15;
    const int b0 = blockIdx.x * RW;

    for (int i = tid; i < (int)(sizeof(Smem) / 4); i += NTHREADS) ((u32*)&S)[i] = 0u;

    // ---- weights -> persistent registers (R6 layout: wave w owns gate tiles w, w+8, w+16) ----
    const bf16x8 zf = {0, 0, 0, 0, 0, 0, 0, 0};
    bf16x8 wihR[3], whhR[3][4], headA[4], headB;
#pragma unroll
    for (int s = 0; s < 3; ++s) {
        const int tw = w + 8 * s;
        wihR[s] = (l < 48) ? ldfrag(wih + (16 * tw + cl) * NI + 8 * g) : zf;
#pragma unroll
        for (int kt = 0; kt < 4; ++kt)
            whhR[s][kt] = ldfrag(whh + (16 * tw + cl) * NH + 32 * kt + 8 * g);
    }
    if (w == 0) {                        // W1 tile 0 (cols 0-15)
#pragma unroll
        for (int kt = 0; kt < 4; ++kt) headA[kt] = ldfrag(w1w + cl * NH + 32 * kt + 8 * g);
    } else if (w == 1) {                 // W1 tile 1 (cols 16-23)
#pragma unroll
        for (int kt = 0; kt < 4; ++kt)
            headA[kt] = (cl < 8) ? ldfrag(w1w + (16 + cl) * NH + 32 * kt + 8 * g) : zf;
    } else if (w == 2) {                 // h2o as B-frag col 0
#pragma unroll
        for (int kt = 0; kt < 4; ++kt)
            headA[kt] = (cl == 0) ? ldfrag(h2ow + 32 * kt + 8 * g) : zf;
    } else {
#pragma unroll
        for (int kt = 0; kt < 4; ++kt) headA[kt] = zf;
    }
    headB = (w == 0) ? ((g < 3) ? ldfrag(w2w + cl * NI + 8 * g) : zf)
          : (w == 1) ? ((g < 3 && cl < 8) ? ldfrag(w2w + (16 + cl) * NI + 8 * g) : zf) : zf;

    // per-lane constants
    const int u = 16 * w + cl;
    const float bR  = bih[u] + bhh[u];
    const float bZ  = bih[128 + u] + bhh[128 + u];
    const float bxN = bih[256 + u];
    const float bhN = bhh[256 + u];
    const float w1b_c = (w == 0) ? w1b_p[cl] : ((w == 1 && cl < 8) ? w1b_p[16 + cl] : 0.0f);
    const float w2b_c = (w == 0) ? w2b_p[cl] : ((w == 1 && cl < 8) ? w2b_p[16 + cl] : 0.0f);
    const float h2ob = h2ob_p[0];

    // h frag addressing (phi(p) = p + ((p>>3)&1) + 2*(p>>4))
    const int ktH = w >> 1;
    const int cc = (2 * w + (cl >> 3)) & 3;
    const int hsB0 = 4 * g + 16 * cc + (g >> 1) + 2 * cc;
    const int eH = cl & 7;
    const int hsl = l + ((l >> 3) & 1) + 2 * (l >> 4);
    // in-register-C lane mapping (waves 0,1): col jC
    const int jC = 16 * w + cl;
    const int cSlotB = ((jC >> 3) & 3) * 16;
    const int cEl = jC & 7;
    const bool isC = (w == 0) || (w == 1 && cl < 8);

    float h_reg[4] = {0.f, 0.f, 0.f, 0.f};

    bar();   // LDS zeroed

    // stage x(0) -> xt[0], x(1) -> xt[1]
    if (tid < 192) {
        int row = tid / 12, c4 = (tid % 12) * 4;
        *(float4*)&S.xt[0][row][c4] = *(const float4*)(x + ((size_t)(b0 + row) * TSTEPS) * 48 + c4);
        *(float4*)&S.xt[1][row][c4] = *(const float4*)(x + ((size_t)(b0 + row) * TSTEPS + 1) * 48 + c4);
    }
    bar();

    // c(0)=h1(0), x(0) frags (rows 0-15)
    if (tid < 384) {
        int rr = tid & 15, j = tid >> 4;
        float xh1 = S.xt[0][rr][j];
        float xh2 = S.xt[0][rr][24 + j];
        int lane = rr + (j >> 3) * 16, el = j & 7;
        u16 hi = f2bf(xh1);
        S.chi[lane][el] = hi;  S.clo[lane][el] = f2bf(xh1 - bf2f(hi));
        S.x1hi[lane][el] = hi;
        S.x2hi[lane][el] = f2bf(xh2);
    }
    // gh(0) carries = biases (h(-1)=0)
    f32x4 gR = {bR, bR, bR, bR};
    f32x4 gZ = {bZ, bZ, bZ, bZ};
    f32x4 gN = {bhN, bhN, bhN, bhN};
    __syncthreads();

    for (int t = 0; t < TSTEPS; ++t) {
        const int nxt = (t + 1) & 1;
        float4 xf;
        const bool isLd = (tid >= 320) && (t + 2 < TSTEPS);
        if (isLd) {   // issue x(t+2) load; stays in flight through P1
            int e = tid - 320, row = e / 12, c4 = (e % 12) * 4;
            xf = *(const float4*)(x + ((size_t)(b0 + row) * TSTEPS + (t + 2)) * 48 + c4);
        }
        // ---- P1: finish gates with c(t); s1/s2 MFMAs (waves 0,1); h update+store ----
        f32x4 aN = {bxN, bxN, bxN, bxN};
        f32x4 s1a, s2a;
        {
            bf16x8 cH = *(const bf16x8*)&S.chi[l][0];
            bf16x8 cL = *(const bf16x8*)&S.clo[l][0];
            gR = MFMA(cH, wihR[0], gR);  gR = MFMA(cL, wihR[0], gR);
            gZ = MFMA(cH, wihR[1], gZ);  gZ = MFMA(cL, wihR[1], gZ);
            aN = MFMA(cH, wihR[2], aN);  aN = MFMA(cL, wihR[2], aN);
        }
        if (w < 2) {
            bf16x8 x1f = *(const bf16x8*)&S.x1hi[l][0];
            bf16x8 x2f = *(const bf16x8*)&S.x2hi[l][0];
            s1a = (f32x4){w2b_c, w2b_c, w2b_c, w2b_c};
            s2a = (f32x4){w2b_c, w2b_c, w2b_c, w2b_c};
            s1a = MFMA(x1f, headB, s1a);
            s2a = MFMA(x2f, headB, s2a);
        }
#pragma unroll
        for (int i = 0; i < 4; ++i) {
            float r = sigm(gR[i]);
            float z = sigm(gZ[i]);
            float n = tanhf_(aN[i] + r * gN[i]);
            float hv = (1.0f - z) * n + z * h_reg[i];
            h_reg[i] = hv;
            S.hhi[ktH][hsB0 + i][eH] = f2bf(hv);
        }
        bar(); // h(t) visible
        // ---- P2: gh(t+1) carries + heads; in-register attention -> c(t+1); x frags ----
        gR = (f32x4){bR, bR, bR, bR};
        gZ = (f32x4){bZ, bZ, bZ, bZ};
        gN = (f32x4){bhN, bhN, bhN, bhN};
        f32x4 whacc = {w1b_c, w1b_c, w1b_c, w1b_c};
#pragma unroll
        for (int kt = 0; kt < 4; ++kt) {
            bf16x8 hH = *(const bf16x8*)&S.hhi[kt][hsl][0];
            gR = MFMA(hH, whhR[0][kt], gR);
            gZ = MFMA(hH, whhR[1][kt], gZ);
            gN = MFMA(hH, whhR[2][kt], gN);
            if (w < 3) whacc = MFMA(hH, headA[kt], whacc);
        }
        if (w == 2) {
            if (cl == 0) {
#pragma unroll
                for (int i = 0; i < 4; ++i)
                    out[(size_t)(b0 + 4 * g + i) * TSTEPS + t] = tanhf_(whacc[i] + h2ob);
            }
        } else if (isC) {   // waves 0,1: a1/a2 -> c(t+1) frags, fully in-register
#pragma unroll
            for (int i = 0; i < 4; ++i) {
                float v = whacc[i];
                float e1 = fexp(tanhf_(v + s1a[i]));
                float e2 = fexp(tanhf_(v + s2a[i]));
                float inv = frcp(e1 + e2);
                int row = 4 * g + i;
                float xh1 = S.xt[nxt][row][jC];
                float xh2 = S.xt[nxt][row][24 + jC];
                float cv = (e1 * inv) * xh1 + (e2 * inv) * xh2;
                u16 hi = f2bf(cv);
                S.chi[row + cSlotB][cEl] = hi;
                S.clo[row + cSlotB][cEl] = f2bf(cv - bf2f(hi));
            }
        }
        if (tid >= 128) {   // x(t+1) A-frags for next step's s1/s2 (384 threads)
            int e = tid - 128, rr = e & 15, j = e >> 4;
            float v1 = S.xt[nxt][rr][j];
            float v2 = S.xt[nxt][rr][24 + j];
            int slot = rr + (j >> 3) * 16, el = j & 7;
            S.x1hi[slot][el] = f2bf(v1);
            S.x2hi[slot][el] = f2bf(v2);
        }
        if (isLd) {         // store x(t+2) into the buffer that becomes xt[nxt] next step
            int e = tid - 320, row = e / 12, c4 = (e % 12) * 4;
            *(float4*)&S.xt[t & 1][row][c4] = xf;
        }
        bar(); // c/x frags + x(t+2) staged
    }
}

extern "C" void kernel_launch(void* const* d_in, const int* in_sizes, int n_in,
                              void* d_out, int out_size, void* d_ws, size_t ws_size,
                              hipStream_t stream) {
    const float* x    = (const float*)d_in[0];
    const float* wih  = (const float*)d_in[1];
    const float* whh  = (const float*)d_in[2];
    const float* bih  = (const float*)d_in[3];
    const float* bhh  = (const float*)d_in[4];
    const float* h2ow = (const float*)d_in[5];
    const float* h2ob = (const float*)d_in[6];
    const float* w1w  = (const float*)d_in[7];
    const float* w1b  = (const float*)d_in[8];
    const float* w2w  = (const float*)d_in[9];
    const float* w2b  = (const float*)d_in[10];
    float* out = (float*)d_out;

    gru_persist<<<NWG, NTHREADS, 0, stream>>>(x, wih, whh, bih, bhh,
                                              h2ow, h2ob, w1w, w1b, w2w, w2b, out);
}